// Round 4
// baseline (1498.431 us; speedup 1.0000x reference)
//
#include <hip/hip_runtime.h>
#include <hip/hip_bf16.h>

// Problem shape (fixed by setup_inputs)
#define MDIM 8192    // B*S = 4*2048
#define NDIM 11008
#define KDIM 4096
#define NKT  128     // KDIM / 32 (K-steps)
#define NBT  86      // NDIM / 128
#define MBT  64      // MDIM / 128
#define NWG  (MBT * NBT)  // 5504, divisible by 8 (XCD swizzle safe)

typedef __attribute__((ext_vector_type(8))) short bf16x8;
typedef __attribute__((ext_vector_type(4))) float f32x4;

// fp32 -> bf16 round-to-nearest-even (no NaN inputs here)
static __device__ __forceinline__ short f2bf(float f) {
    unsigned u = __builtin_bit_cast(unsigned, f);
    unsigned r = (u + 0x7FFFu + ((u >> 16) & 1u)) >> 16;
    return (short)(unsigned short)r;
}

// ---------------------------------------------------------------------------
// Shared MFMA tile compute: 4 waves in 2x2, each owns a 64x64 sub-tile of the
// 128x128 block. A-LDS rows are M, B-LDS rows are N (B^T layout), both with
// contiguous K so fragment loads are single ds_read_b128.
// a_frag: A[row = lane&15][k = (lane>>4)*8 + j]
// b_frag: B[k = (lane>>4)*8 + j][col = lane&15]
// acc   : D[row = (lane>>4)*4 + j][col = lane&15]   (m89-verified layout)
// ---------------------------------------------------------------------------
template <int LDT>
static __device__ __forceinline__ void mma_step(
    const short (*As)[LDT], const short (*Bs)[LDT], f32x4 acc[4][4], int tid)
{
    const int lane = tid & 63;
    const int wid  = tid >> 6;
    const int wm = (wid >> 1) * 64;
    const int wn = (wid & 1) * 64;
    const int r  = lane & 15;
    const int ko = (lane >> 4) * 8;
    bf16x8 af[4], bfr[4];
#pragma unroll
    for (int i = 0; i < 4; ++i)
        af[i] = *(const bf16x8*)&As[wm + i * 16 + r][ko];
#pragma unroll
    for (int i = 0; i < 4; ++i)
        bfr[i] = *(const bf16x8*)&Bs[wn + i * 16 + r][ko];
#pragma unroll
    for (int mi = 0; mi < 4; ++mi)
#pragma unroll
        for (int ni = 0; ni < 4; ++ni)
            acc[mi][ni] = __builtin_amdgcn_mfma_f32_16x16x32_bf16(
                af[mi], bfr[ni], acc[mi][ni], 0, 0, 0);
}

static __device__ __forceinline__ void epilogue(
    float* __restrict__ out, const f32x4 acc[4][4], int row0, int col0, int tid)
{
    const int lane = tid & 63;
    const int wid  = tid >> 6;
    const int wm = (wid >> 1) * 64;
    const int wn = (wid & 1) * 64;
    const int r4 = (lane >> 4) * 4;
    const int c  = lane & 15;
#pragma unroll
    for (int mi = 0; mi < 4; ++mi)
#pragma unroll
        for (int ni = 0; ni < 4; ++ni)
#pragma unroll
            for (int j = 0; j < 4; ++j) {
                size_t rr = (size_t)(row0 + wm + mi * 16 + r4 + j);
                size_t cc = (size_t)(col0 + wn + ni * 16 + c);
                out[rr * NDIM + cc] = acc[mi][ni][j];
            }
}

// ---------------------------------------------------------------------------
// Prepass 1: x (fp32, M x K) -> xb (bf16, M x K). 8 elems/thread.
// ---------------------------------------------------------------------------
__global__ __launch_bounds__(256) void k_cvt_x(
    const float* __restrict__ x, short* __restrict__ xb)
{
    size_t i = ((size_t)blockIdx.x * 256 + threadIdx.x) * 8;
    float4 f0 = *(const float4*)(x + i);
    float4 f1 = *(const float4*)(x + i + 4);
    bf16x8 v;
    v[0] = f2bf(f0.x); v[1] = f2bf(f0.y); v[2] = f2bf(f0.z); v[3] = f2bf(f0.w);
    v[4] = f2bf(f1.x); v[5] = f2bf(f1.y); v[6] = f2bf(f1.z); v[7] = f2bf(f1.w);
    *(bf16x8*)(xb + i) = v;
}

// ---------------------------------------------------------------------------
// Prepass 2: dequant qweight -> wt = W^T (bf16, N x K, contiguous K).
// thread: one n, 4 consecutive qweight rows -> 32 contiguous k (64B store).
// w[k,n] = scales[g,n] * (((qw[k>>3,n] >> 4*(k&7)) & 0xF) - z[g,n]),  g = k>>7
// ---------------------------------------------------------------------------
__global__ __launch_bounds__(256) void k_dequant(
    const int* __restrict__ qw, const float* __restrict__ sc,
    const int* __restrict__ qz, short* __restrict__ wt)
{
    const int n   = blockIdx.x * 256 + threadIdx.x;   // 0..11007
    const int kr4 = blockIdx.y;                       // 0..127 -> qweight rows kr4*4..+3
    const int g   = (kr4 * 32) >> 7;
    const float s = sc[(size_t)g * NDIM + n];
    const int z   = (qz[(size_t)g * (NDIM / 8) + (n >> 3)] >> ((n & 7) * 4)) & 15;
    const float fz = (float)(8388608 + z);            // 2^23 + z, exact
    const int* qp = qw + (size_t)(kr4 * 4) * NDIM + n;
    short* op = wt + (size_t)n * KDIM + kr4 * 32;
#pragma unroll
    for (int r = 0; r < 4; ++r) {
        unsigned u = (unsigned)qp[(size_t)r * NDIM];
        bf16x8 v;
#pragma unroll
        for (int j = 0; j < 8; ++j) {
            unsigned fq = 0x4B000000u | ((u >> (4 * j)) & 0xFu);  // 2^23 + q
            // exact (Sterbenz) subtraction -> s * (q - z) with single rounding
            v[j] = f2bf((__builtin_bit_cast(float, fq) - fz) * s);
        }
        *(bf16x8*)(op + r * 8) = v;
    }
}

// ---------------------------------------------------------------------------
// Main GEMM (prepass path): m97 structure. 128x128 tile, BK=32, 4 waves,
// global_load_lds width=16 for both operands, linear [128][32] LDS.
// ---------------------------------------------------------------------------
#define GLD_LDS(g, l) \
    __builtin_amdgcn_global_load_lds( \
        (const __attribute__((address_space(1))) void*)(g), \
        (__attribute__((address_space(3))) void*)(l), 16, 0, 0)

__global__ __launch_bounds__(256) void k_gemm(
    const short* __restrict__ xb, const short* __restrict__ wt,
    float* __restrict__ out)
{
    __shared__ alignas(16) short As[128][32];
    __shared__ alignas(16) short Bs[128][32];

    const int tid = threadIdx.x;
    // XCD-aware swizzle (bijective: 5504 % 8 == 0)
    const int wgs = ((int)blockIdx.x & 7) * (NWG / 8) + ((int)blockIdx.x >> 3);
    const int bm = wgs / NBT, bn = wgs % NBT;
    const int row0 = bm * 128, col0 = bn * 128;

    // staging: thread t -> row t>>2 (and +64), 16B chunk t&3.
    // LDS dest is wave-uniform base + lane*16 == linear [row][k] layout.
    const int sr  = tid >> 2;
    const int sc8 = (tid & 3) * 8;
    const short* pA0 = xb + (size_t)(row0 + sr) * KDIM + sc8;
    const short* pA1 = xb + (size_t)(row0 + sr + 64) * KDIM + sc8;
    const short* pB0 = wt + (size_t)(col0 + sr) * KDIM + sc8;
    const short* pB1 = wt + (size_t)(col0 + sr + 64) * KDIM + sc8;

    const int wid = tid >> 6;
    char* lA = (char*)&As[0][0] + wid * 1024;
    char* lB = (char*)&Bs[0][0] + wid * 1024;

    f32x4 acc[4][4];
#pragma unroll
    for (int i = 0; i < 4; ++i)
#pragma unroll
        for (int j = 0; j < 4; ++j)
            acc[i][j] = f32x4{0.f, 0.f, 0.f, 0.f};

#pragma unroll 1
    for (int kt = 0; kt < NKT; ++kt) {
        const int ko = kt * 32;
        GLD_LDS(pA0 + ko, lA);
        GLD_LDS(pA1 + ko, lA + 4096);
        GLD_LDS(pB0 + ko, lB);
        GLD_LDS(pB1 + ko, lB + 4096);
        __syncthreads();
        mma_step<32>(As, Bs, acc, tid);
        __syncthreads();
    }
    epilogue(out, acc, row0, col0, tid);
}

// ---------------------------------------------------------------------------
// Fallback: fully fused (no workspace). Reg-staged, padded LDS (stride 40).
// ---------------------------------------------------------------------------
__global__ __launch_bounds__(256) void k_fused(
    const float* __restrict__ x, const int* __restrict__ qw,
    const float* __restrict__ sc, const int* __restrict__ qz,
    float* __restrict__ out)
{
    __shared__ alignas(16) short As[128][40];
    __shared__ alignas(16) short Bs[128][40];

    const int tid = threadIdx.x;
    const int wgs = ((int)blockIdx.x & 7) * (NWG / 8) + ((int)blockIdx.x >> 3);
    const int bm = wgs / NBT, bn = wgs % NBT;
    const int row0 = bm * 128, col0 = bn * 128;

    // A staging: thread -> row tid>>1, 16-float half (tid&1)
    const int ar = tid >> 1;
    const int ac = (tid & 1) * 16;
    const float* ap = x + (size_t)(row0 + ar) * KDIM + ac;

    // B staging: thread -> col nt, qweight-rows {kr0, kr0+2} of the 4-row tile
    const int nt   = tid & 127;
    const int kr0  = tid >> 7;
    const int gcol = col0 + nt;
    const int* qp   = qw + gcol;
    const float* sp = sc + gcol;
    const int* zp   = qz + (gcol >> 3);
    const int zsh   = (gcol & 7) * 4;

    float4 pa0, pa1, pa2, pa3;
    unsigned pq0, pq1;
    float psc, pfz;

    auto loadt = [&](int kt) {
        const float* a = ap + kt * 32;
        pa0 = *(const float4*)(a);
        pa1 = *(const float4*)(a + 4);
        pa2 = *(const float4*)(a + 8);
        pa3 = *(const float4*)(a + 12);
        const int* q = qp + (size_t)kt * 4 * NDIM;
        pq0 = (unsigned)q[(size_t)kr0 * NDIM];
        pq1 = (unsigned)q[(size_t)(kr0 + 2) * NDIM];
        const int g = kt >> 2;
        psc = sp[(size_t)g * NDIM];
        pfz = (float)(8388608 + ((zp[(size_t)g * (NDIM / 8)] >> zsh) & 15));
    };

    auto writet = [&]() {
        bf16x8 v0, v1;
        v0[0] = f2bf(pa0.x); v0[1] = f2bf(pa0.y); v0[2] = f2bf(pa0.z); v0[3] = f2bf(pa0.w);
        v0[4] = f2bf(pa1.x); v0[5] = f2bf(pa1.y); v0[6] = f2bf(pa1.z); v0[7] = f2bf(pa1.w);
        v1[0] = f2bf(pa2.x); v1[1] = f2bf(pa2.y); v1[2] = f2bf(pa2.z); v1[3] = f2bf(pa2.w);
        v1[4] = f2bf(pa3.x); v1[5] = f2bf(pa3.y); v1[6] = f2bf(pa3.z); v1[7] = f2bf(pa3.w);
        *(bf16x8*)&As[ar][ac]     = v0;
        *(bf16x8*)&As[ar][ac + 8] = v1;
        bf16x8 w0, w1;
#pragma unroll
        for (int j = 0; j < 8; ++j) {
            unsigned f0b = 0x4B000000u | ((pq0 >> (4 * j)) & 0xFu);
            unsigned f1b = 0x4B000000u | ((pq1 >> (4 * j)) & 0xFu);
            w0[j] = f2bf((__builtin_bit_cast(float, f0b) - pfz) * psc);
            w1[j] = f2bf((__builtin_bit_cast(float, f1b) - pfz) * psc);
        }
        *(bf16x8*)&Bs[nt][kr0 * 8]       = w0;
        *(bf16x8*)&Bs[nt][(kr0 + 2) * 8] = w1;
    };

    f32x4 acc[4][4];
#pragma unroll
    for (int i = 0; i < 4; ++i)
#pragma unroll
        for (int j = 0; j < 4; ++j)
            acc[i][j] = f32x4{0.f, 0.f, 0.f, 0.f};

    loadt(0);
#pragma unroll 1
    for (int kt = 0; kt < NKT; ++kt) {
        writet();
        __syncthreads();
        if (kt + 1 < NKT) loadt(kt + 1);   // prefetch hides under MFMA
        mma_step<40>(As, Bs, acc, tid);
        __syncthreads();
    }
    epilogue(out, acc, row0, col0, tid);
}

// ---------------------------------------------------------------------------
extern "C" void kernel_launch(void* const* d_in, const int* in_sizes, int n_in,
                              void* d_out, int out_size, void* d_ws, size_t ws_size,
                              hipStream_t stream) {
    const float* x  = (const float*)d_in[0];
    const int*   qw = (const int*)d_in[1];
    const float* sc = (const float*)d_in[2];
    const int*   qz = (const int*)d_in[3];
    float* out = (float*)d_out;

    const size_t xb_bytes = (size_t)MDIM * KDIM * 2;   // 67,108,864
    const size_t wt_bytes = (size_t)NDIM * KDIM * 2;   // 90,177,536

    if (ws_size >= xb_bytes + wt_bytes) {
        short* xb = (short*)d_ws;
        short* wt = (short*)((char*)d_ws + xb_bytes);
        k_cvt_x<<<(MDIM * (size_t)KDIM / 8) / 256, 256, 0, stream>>>(x, xb);
        k_dequant<<<dim3(NDIM / 256, 128), 256, 0, stream>>>(qw, sc, qz, wt);
        k_gemm<<<NWG, 256, 0, stream>>>(xb, wt, out);
    } else {
        k_fused<<<NWG, 256, 0, stream>>>(x, qw, sc, qz, out);
    }
}